// Round 1
// baseline (1694.853 us; speedup 1.0000x reference)
//
#include <hip/hip_runtime.h>
#include <stdint.h>

#define T_TOK 4096
#define HDIM 2048
#define MDIM 1408
#define NEXP 28
#define TOPK 6
#define NPAIR (T_TOK*TOPK)   // 24576

typedef short short8 __attribute__((ext_vector_type(8)));
typedef float f32x4 __attribute__((ext_vector_type(4)));

__device__ __forceinline__ unsigned short f2bf(float x){
  unsigned int u = __float_as_uint(x);
  u += 0x7fffu + ((u >> 16) & 1u);
  return (unsigned short)(u >> 16);
}
__device__ __forceinline__ float bf2f(unsigned int h){
  return __uint_as_float(h << 16);
}

// ---------------- x fp32 -> bf16 ----------------
__global__ __launch_bounds__(256) void cvt_kernel(const float* __restrict__ x,
                                                  unsigned short* __restrict__ xb, int n8){
  int i = blockIdx.x*256 + threadIdx.x;
  if (i >= n8) return;
  const float4* s = (const float4*)x + (size_t)i*2;
  float4 a = s[0], b = s[1];
  unsigned int w0 = (unsigned)f2bf(a.x) | ((unsigned)f2bf(a.y)<<16);
  unsigned int w1 = (unsigned)f2bf(a.z) | ((unsigned)f2bf(a.w)<<16);
  unsigned int w2 = (unsigned)f2bf(b.x) | ((unsigned)f2bf(b.y)<<16);
  unsigned int w3 = (unsigned)f2bf(b.z) | ((unsigned)f2bf(b.w)<<16);
  uint4 o = {w0,w1,w2,w3};
  ((uint4*)xb)[i] = o;
}

// ---------------- gating: logits -> softmax -> top6 ----------------
__global__ __launch_bounds__(256) void gate_kernel(const float* __restrict__ x,
                                                   const float* __restrict__ gw,
                                                   int* __restrict__ topk_idx,
                                                   float* __restrict__ topk_w,
                                                   int* __restrict__ counts){
  const int wave = threadIdx.x >> 6, lane = threadIdx.x & 63;
  const int t = blockIdx.x*4 + wave;
  const float* xr = x + (size_t)t*HDIM;
  float xv[32];
  #pragma unroll
  for (int i=0;i<32;i++) xv[i] = xr[lane + 64*i];
  float sc[NEXP];
  #pragma unroll
  for (int e=0;e<NEXP;e++){
    const float* g = gw + (size_t)e*HDIM + lane;
    float a = 0.f;
    #pragma unroll
    for (int i=0;i<32;i++) a += xv[i]*g[64*i];
    #pragma unroll
    for (int d=32; d>0; d>>=1) a += __shfl_xor(a, d);
    sc[e] = a;
  }
  float mx = sc[0];
  #pragma unroll
  for (int e=1;e<NEXP;e++) mx = fmaxf(mx, sc[e]);
  unsigned int mask=0; int bi[TOPK]; float bs[TOPK]; float bsum=0.f;
  #pragma unroll
  for (int k=0;k<TOPK;k++){
    float bm=-3.4e38f; int bj=0;
    #pragma unroll
    for (int e=0;e<NEXP;e++){
      bool ok = (((mask>>e)&1u)==0u) && (sc[e]>bm);
      bm = ok ? sc[e] : bm; bj = ok ? e : bj;
    }
    mask |= (1u<<bj);
    float s = expf(bm - mx);
    bi[k]=bj; bs[k]=s; bsum+=s;
  }
  if (lane==0){
    float inv = 1.f/(bsum + 1e-20f);
    #pragma unroll
    for (int k=0;k<TOPK;k++){
      topk_idx[t*TOPK+k]=bi[k];
      topk_w[t*TOPK+k]=bs[k]*inv;
      atomicAdd(&counts[bi[k]],1);
    }
  }
}

// ---------------- scan + fill dispatch lists ----------------
__global__ void scan_kernel(const int* __restrict__ counts, int* __restrict__ offsets,
                            int* __restrict__ cursor){
  int t = threadIdx.x;
  if (t < NEXP) cursor[t] = 0;
  if (t == 0){
    int s = 0;
    for (int e=0;e<NEXP;e++){ offsets[e]=s; s+=counts[e]; }
    offsets[NEXP]=s;
  }
}

__global__ __launch_bounds__(256) void fill_kernel(const int* __restrict__ topk_idx,
                                                   const float* __restrict__ topk_w,
                                                   const int* __restrict__ offsets,
                                                   int* __restrict__ cursor,
                                                   int* __restrict__ pair_token,
                                                   float* __restrict__ pair_w){
  int t = blockIdx.x*256 + threadIdx.x;
  if (t >= T_TOK) return;
  #pragma unroll
  for (int k=0;k<TOPK;k++){
    int e = topk_idx[t*TOPK+k];
    int pos = atomicAdd(&cursor[e],1);
    int p = offsets[e]+pos;
    pair_token[p]=t;
    pair_w[p]=topk_w[t*TOPK+k];
  }
}

// ---------------- grouped GEMM ----------------
// A (bf16, rows [*,K]) x B (fp32 [E][K][N], converted to bf16 at staging) -> C tile [128x128]
// GATHER: A row = xb[pair_token[p]]; else A row = Abase[p] directly.
// EPI 0: store bf16 rows to Cstore[p*N+col].  EPI 1: atomicAdd(w_p * acc) into Out[tok*N+col].
template<bool GATHER, int EPI>
__global__ __launch_bounds__(256) void gemm_moe(
    const unsigned short* __restrict__ Abase,
    const float* __restrict__ Bbase,
    unsigned short* __restrict__ Cstore,
    float* __restrict__ Out,
    const int* __restrict__ counts, const int* __restrict__ offsets,
    const int* __restrict__ pair_token, const float* __restrict__ pair_w,
    int K, int N)
{
  const int e = blockIdx.z;
  const int cnt = counts[e];
  const int row0 = blockIdx.y * 128;
  if (row0 >= cnt) return;
  const int off = offsets[e];
  const int n0 = blockIdx.x * 128;

  __shared__ unsigned short Alds[128][40];  // [m][k], padded to 40 (80B rows, 16B aligned)
  __shared__ unsigned short Blds[128][40];  // [n][k] transposed

  const int tid = threadIdx.x;
  // A staging: thread -> (row ar, octet-half aoc)
  const int ar = tid & 127;
  const int aoc = tid >> 7;                 // 0/1
  const int pA = off + min(row0 + ar, cnt-1);
  const unsigned short* Arow;
  if (GATHER) Arow = Abase + (size_t)pair_token[pA]*K;
  else        Arow = Abase + (size_t)pA*K;
  // B staging: thread -> (col bn, k-octet-half bkg)
  const int bn = tid & 127;
  const int bkg = tid >> 7;
  const float* Bp = Bbase + (size_t)e*K*N + n0 + bn;

  const int lane = tid & 63, wid = tid >> 6;
  const int wm = wid >> 1, wn = wid & 1;    // 2x2 wave grid, 64x64 per wave
  const int lrow = lane & 15, lgrp = lane >> 4;

  f32x4 acc[4][4] = {};

  for (int kt = 0; kt < K; kt += 32){
    __syncthreads();
    { // stage A: 2 x 16B per thread (gathered rows)
      const uint4* s = (const uint4*)(Arow + kt);
      uint4 v0 = s[aoc], v1 = s[aoc+2];
      *(uint4*)&Alds[ar][8*aoc]     = v0;
      *(uint4*)&Alds[ar][8*(aoc+2)] = v1;
    }
    #pragma unroll
    for (int g2 = 0; g2 < 2; ++g2){ // stage B transposed, convert fp32->bf16
      int g = bkg + 2*g2;
      float f[8];
      #pragma unroll
      for (int i=0;i<8;i++) f[i] = Bp[(size_t)(kt + 8*g + i)*N];
      unsigned int w[4];
      #pragma unroll
      for (int i=0;i<4;i++) w[i] = (unsigned)f2bf(f[2*i]) | ((unsigned)f2bf(f[2*i+1])<<16);
      uint4 v = {w[0],w[1],w[2],w[3]};
      *(uint4*)&Blds[bn][8*g] = v;
    }
    __syncthreads();
    short8 af[4], bfr[4];
    #pragma unroll
    for (int fm=0;fm<4;fm++) af[fm]  = *(const short8*)&Alds[wm*64+fm*16+lrow][8*lgrp];
    #pragma unroll
    for (int fn=0;fn<4;fn++) bfr[fn] = *(const short8*)&Blds[wn*64+fn*16+lrow][8*lgrp];
    #pragma unroll
    for (int fm=0;fm<4;fm++)
      #pragma unroll
      for (int fn=0;fn<4;fn++)
        acc[fm][fn] = __builtin_amdgcn_mfma_f32_16x16x32_bf16(af[fm], bfr[fn], acc[fm][fn], 0,0,0);
  }

  if (EPI == 0){
    #pragma unroll
    for (int fm=0;fm<4;fm++){
      #pragma unroll
      for (int j=0;j<4;j++){
        int grow = wm*64 + fm*16 + lgrp*4 + j;
        if (row0 + grow < cnt){
          size_t p = (size_t)(off + row0 + grow);
          #pragma unroll
          for (int fn=0;fn<4;fn++){
            int col = n0 + wn*64 + fn*16 + lrow;
            Cstore[p*(size_t)N + col] = f2bf(acc[fm][fn][j]);
          }
        }
      }
    }
  } else {
    #pragma unroll
    for (int fm=0;fm<4;fm++){
      #pragma unroll
      for (int j=0;j<4;j++){
        int grow = wm*64 + fm*16 + lgrp*4 + j;
        if (row0 + grow < cnt){
          int p = off + row0 + grow;
          int tok = pair_token[p];
          float wgt = pair_w[p];
          float* orow = Out + (size_t)tok*N;
          #pragma unroll
          for (int fn=0;fn<4;fn++){
            int col = n0 + wn*64 + fn*16 + lrow;
            atomicAdd(orow + col, wgt*acc[fm][fn][j]);
          }
        }
      }
    }
  }
}

// ---------------- h = silu(g) * u (in place on g) ----------------
__global__ __launch_bounds__(256) void silu_mul_kernel(unsigned short* __restrict__ g,
                                                       const unsigned short* __restrict__ u,
                                                       long n8){
  long i = blockIdx.x*(long)256 + threadIdx.x;
  if (i >= n8) return;
  uint4 gv = ((const uint4*)g)[i];
  uint4 uv = ((const uint4*)u)[i];
  unsigned int gi[4] = {gv.x,gv.y,gv.z,gv.w};
  unsigned int ui[4] = {uv.x,uv.y,uv.z,uv.w};
  unsigned int r[4];
  #pragma unroll
  for (int w=0;w<4;w++){
    float g0 = bf2f(gi[w]&0xffffu), g1 = bf2f(gi[w]>>16);
    float u0 = bf2f(ui[w]&0xffffu), u1 = bf2f(ui[w]>>16);
    float h0 = g0*u0/(1.f+expf(-g0));
    float h1 = g1*u1/(1.f+expf(-g1));
    r[w] = (unsigned)f2bf(h0) | ((unsigned)f2bf(h1)<<16);
  }
  uint4 o = {r[0],r[1],r[2],r[3]};
  ((uint4*)g)[i] = o;
}

extern "C" void kernel_launch(void* const* d_in, const int* in_sizes, int n_in,
                              void* d_out, int out_size, void* d_ws, size_t ws_size,
                              hipStream_t stream) {
  const float* x  = (const float*)d_in[0];
  const float* gw = (const float*)d_in[1];
  const float* wg = (const float*)d_in[2];
  const float* wu = (const float*)d_in[3];
  const float* wd = (const float*)d_in[4];
  float* out = (float*)d_out;

  char* p = (char*)d_ws;
  unsigned short* xb   = (unsigned short*)p; p += (size_t)T_TOK*HDIM*2;   // 16.8 MB
  unsigned short* buf1 = (unsigned short*)p; p += (size_t)NPAIR*MDIM*2;   // 69.2 MB (g, then h)
  unsigned short* buf2 = (unsigned short*)p; p += (size_t)NPAIR*MDIM*2;   // 69.2 MB (u)
  int*   topk_idx   = (int*)p;   p += NPAIR*4;
  float* topk_w     = (float*)p; p += NPAIR*4;
  int*   pair_token = (int*)p;   p += NPAIR*4;
  float* pair_w     = (float*)p; p += NPAIR*4;
  int*   counts     = (int*)p;   p += 128;
  int*   offsets    = (int*)p;   p += 128;
  int*   cursor     = (int*)p;   p += 128;

  hipMemsetAsync(counts, 0, 128, stream);
  cvt_kernel<<<T_TOK*HDIM/8/256, 256, 0, stream>>>(x, xb, T_TOK*HDIM/8);
  gate_kernel<<<T_TOK/4, 256, 0, stream>>>(x, gw, topk_idx, topk_w, counts);
  scan_kernel<<<1, 64, 0, stream>>>(counts, offsets, cursor);
  fill_kernel<<<T_TOK/256, 256, 0, stream>>>(topk_idx, topk_w, offsets, cursor, pair_token, pair_w);

  dim3 g1(MDIM/128, T_TOK/128, NEXP);
  gemm_moe<true,0><<<g1, 256, 0, stream>>>(xb, wg, buf1, nullptr, counts, offsets,
                                           pair_token, pair_w, HDIM, MDIM);
  gemm_moe<true,0><<<g1, 256, 0, stream>>>(xb, wu, buf2, nullptr, counts, offsets,
                                           pair_token, pair_w, HDIM, MDIM);
  silu_mul_kernel<<<(int)((NPAIR*(long)MDIM/8 + 255)/256), 256, 0, stream>>>(buf1, buf2, NPAIR*(long)MDIM/8);

  hipMemsetAsync(out, 0, (size_t)out_size*4, stream);
  dim3 g3(HDIM/128, T_TOK/128, NEXP);
  gemm_moe<false,1><<<g3, 256, 0, stream>>>(buf1, wd, nullptr, out, counts, offsets,
                                            pair_token, pair_w, MDIM, HDIM);
}

// Round 2
// 1211.877 us; speedup vs baseline: 1.3985x; 1.3985x over previous
//
#include <hip/hip_runtime.h>
#include <stdint.h>

#define T_TOK 4096
#define HDIM 2048
#define MDIM 1408
#define NEXP 28
#define TOPK 6
#define NPAIR (T_TOK*TOPK)   // 24576

typedef unsigned short u16;
typedef short short8 __attribute__((ext_vector_type(8)));
typedef float f32x4 __attribute__((ext_vector_type(4)));

__device__ __forceinline__ u16 f2bf(float x){
  unsigned int u = __float_as_uint(x);
  u += 0x7fffu + ((u >> 16) & 1u);
  return (u16)(u >> 16);
}

__device__ __forceinline__ void gload16(const u16* g, u16* l){
  __builtin_amdgcn_global_load_lds((const __attribute__((address_space(1))) unsigned int*)g,
                                   (__attribute__((address_space(3))) unsigned int*)l,
                                   16, 0, 0);
}

// ---------------- x fp32 -> bf16 ----------------
__global__ __launch_bounds__(256) void cvt_kernel(const float* __restrict__ x,
                                                  u16* __restrict__ xb, int n8){
  int i = blockIdx.x*256 + threadIdx.x;
  if (i >= n8) return;
  const float4* s = (const float4*)x + (size_t)i*2;
  float4 a = s[0], b = s[1];
  unsigned int w0 = (unsigned)f2bf(a.x) | ((unsigned)f2bf(a.y)<<16);
  unsigned int w1 = (unsigned)f2bf(a.z) | ((unsigned)f2bf(a.w)<<16);
  unsigned int w2 = (unsigned)f2bf(b.x) | ((unsigned)f2bf(b.y)<<16);
  unsigned int w3 = (unsigned)f2bf(b.z) | ((unsigned)f2bf(b.w)<<16);
  uint4 o = {w0,w1,w2,w3};
  ((uint4*)xb)[i] = o;
}

// ---------------- transpose + convert: in [E][K][N] fp32 -> out [E][N][K] bf16 ----------------
__global__ __launch_bounds__(256) void transpose_cvt(const float* __restrict__ in,
                                                     u16* __restrict__ out, int K, int N){
  const int e = blockIdx.z;
  const int n0 = blockIdx.x*64, k0 = blockIdx.y*64;
  const float* src = in + ((size_t)e*K + k0)*N + n0;
  u16* dst = out + ((size_t)e*N + n0)*K + k0;
  __shared__ u16 td[64][65];
  const int tid = threadIdx.x;
  const int rk = tid>>4, rn = (tid&15)*4;
  #pragma unroll
  for (int i=0;i<4;i++){
    int k = rk + 16*i;
    float4 v = *(const float4*)(src + (size_t)k*N + rn);
    td[k][rn+0]=f2bf(v.x); td[k][rn+1]=f2bf(v.y);
    td[k][rn+2]=f2bf(v.z); td[k][rn+3]=f2bf(v.w);
  }
  __syncthreads();
  const int wn = tid>>4, wk = (tid&15)*4;
  #pragma unroll
  for (int i=0;i<4;i++){
    int n = wn + 16*i;
    unsigned int lo = (unsigned)td[wk+0][n] | ((unsigned)td[wk+1][n]<<16);
    unsigned int hi = (unsigned)td[wk+2][n] | ((unsigned)td[wk+3][n]<<16);
    uint2 o = {lo, hi};
    *(uint2*)(dst + (size_t)n*K + wk) = o;
  }
}

// ---------------- gating: logits -> softmax -> top6 ----------------
__global__ __launch_bounds__(256) void gate_kernel(const float* __restrict__ x,
                                                   const float* __restrict__ gw,
                                                   int* __restrict__ topk_idx,
                                                   float* __restrict__ topk_w,
                                                   int* __restrict__ counts){
  const int wave = threadIdx.x >> 6, lane = threadIdx.x & 63;
  const int t = blockIdx.x*4 + wave;
  const float* xr = x + (size_t)t*HDIM;
  float xv[32];
  #pragma unroll
  for (int i=0;i<32;i++) xv[i] = xr[lane + 64*i];
  float sc[NEXP];
  #pragma unroll
  for (int e=0;e<NEXP;e++){
    const float* g = gw + (size_t)e*HDIM + lane;
    float a = 0.f;
    #pragma unroll
    for (int i=0;i<32;i++) a += xv[i]*g[64*i];
    #pragma unroll
    for (int d=32; d>0; d>>=1) a += __shfl_xor(a, d);
    sc[e] = a;
  }
  float mx = sc[0];
  #pragma unroll
  for (int e=1;e<NEXP;e++) mx = fmaxf(mx, sc[e]);
  unsigned int mask=0; int bi[TOPK]; float bs[TOPK]; float bsum=0.f;
  #pragma unroll
  for (int k=0;k<TOPK;k++){
    float bm=-3.4e38f; int bj=0;
    #pragma unroll
    for (int e=0;e<NEXP;e++){
      bool ok = (((mask>>e)&1u)==0u) && (sc[e]>bm);
      bm = ok ? sc[e] : bm; bj = ok ? e : bj;
    }
    mask |= (1u<<bj);
    float s = expf(bm - mx);
    bi[k]=bj; bs[k]=s; bsum+=s;
  }
  if (lane==0){
    float inv = 1.f/(bsum + 1e-20f);
    #pragma unroll
    for (int k=0;k<TOPK;k++){
      topk_idx[t*TOPK+k]=bi[k];
      topk_w[t*TOPK+k]=bs[k]*inv;
      atomicAdd(&counts[bi[k]],1);
    }
  }
}

// ---------------- scan + fill dispatch lists ----------------
__global__ void scan_kernel(const int* __restrict__ counts, int* __restrict__ offsets,
                            int* __restrict__ cursor){
  int t = threadIdx.x;
  if (t < NEXP) cursor[t] = 0;
  if (t == 0){
    int s = 0;
    for (int e=0;e<NEXP;e++){ offsets[e]=s; s+=counts[e]; }
    offsets[NEXP]=s;
  }
}

__global__ __launch_bounds__(256) void fill_kernel(const int* __restrict__ topk_idx,
                                                   const float* __restrict__ topk_w,
                                                   const int* __restrict__ offsets,
                                                   int* __restrict__ cursor,
                                                   int* __restrict__ pair_token,
                                                   float* __restrict__ pair_w){
  int t = blockIdx.x*256 + threadIdx.x;
  if (t >= T_TOK) return;
  #pragma unroll
  for (int k=0;k<TOPK;k++){
    int e = topk_idx[t*TOPK+k];
    int pos = atomicAdd(&cursor[e],1);
    int p = offsets[e]+pos;
    pair_token[p]=t;
    pair_w[p]=topk_w[t*TOPK+k];
  }
}

// ---------------- grouped GEMM, BK=64, global_load_lds + XOR swizzle ----------------
// A rows bf16 [*,K]; B [E][N][K] bf16 (pre-transposed). Tile 128x128, 4 waves 2x2.
// NB==2: B0=w_gate, B1=w_up, epilogue h = silu(g)*u -> Hout bf16.
// NB==1: epilogue atomicAdd(pair_w * acc) into Out[tok][col].
template<int NB, bool GATHER, int EPI>
__global__ __launch_bounds__(256,2) void gemm2(
    const u16* __restrict__ Ab, const u16* __restrict__ B0, const u16* __restrict__ B1,
    u16* __restrict__ Hout, float* __restrict__ Out,
    const int* __restrict__ counts, const int* __restrict__ offsets,
    const int* __restrict__ pair_token, const float* __restrict__ pair_w,
    int K, int N)
{
  const int e = blockIdx.z;
  const int cnt = counts[e];
  const int row0 = blockIdx.y*128;
  if (row0 >= cnt) return;
  const int off = offsets[e];
  const int n0 = blockIdx.x*128;

  __shared__ u16 smem[(1+NB)*8192];   // A | B0 | (B1)

  const int tid = threadIdx.x;
  const int lane = tid&63, wid = tid>>6;
  const int wm = wid>>1, wn = wid&1;
  const int lrow = lane&15, lgrp = lane>>4;

  // staging source pointers (swizzle baked into the global source chunk)
  const u16* ap[4]; const u16* bp0[4]; const u16* bp1[4];
  #pragma unroll
  for (int i=0;i<4;i++){
    int c = tid + 256*i;          // chunk id: row = c>>3, 16B-chunk = c&7
    int r = c>>3;
    int sc = (c&7) ^ (r&7);
    int pr = off + min(row0 + r, cnt-1);
    const u16* arow = GATHER ? (Ab + (size_t)pair_token[pr]*K) : (Ab + (size_t)pr*K);
    ap[i] = arow + sc*8;
    size_t brow = (size_t)e*N + (size_t)(n0 + r);
    bp0[i] = B0 + brow*K + sc*8;
    if (NB==2) bp1[i] = B1 + brow*K + sc*8;
  }

  // fragment LDS offsets (u16 units), swizzled to match
  int aoffs[2][4], boffs[2][4];
  #pragma unroll
  for (int kh=0;kh<2;kh++){
    #pragma unroll
    for (int f=0; f<4; f++){
      int mr = wm*64 + f*16 + lrow;
      aoffs[kh][f] = mr*64 + (((kh*4+lgrp) ^ (mr&7))*8);
      int nr = wn*64 + f*16 + lrow;
      boffs[kh][f] = nr*64 + (((kh*4+lgrp) ^ (nr&7))*8);
    }
  }

  f32x4 acc0[4][4] = {};
  f32x4 acc1[4][4] = {};

  for (int kt=0; kt<K; kt+=64){
    __syncthreads();
    #pragma unroll
    for (int i=0;i<4;i++){
      int ldo = (tid + 256*i)*8;
      gload16(ap[i] + kt, &smem[ldo]);
      gload16(bp0[i] + kt, &smem[8192 + ldo]);
      if (NB==2) gload16(bp1[i] + kt, &smem[16384 + ldo]);
    }
    __syncthreads();
    #pragma unroll
    for (int kh=0; kh<2; kh++){
      short8 af[4], b0f[4], b1f[4];
      #pragma unroll
      for (int f=0;f<4;f++){
        af[f]  = *(const short8*)&smem[aoffs[kh][f]];
        b0f[f] = *(const short8*)&smem[8192 + boffs[kh][f]];
        if (NB==2) b1f[f] = *(const short8*)&smem[16384 + boffs[kh][f]];
      }
      #pragma unroll
      for (int fm=0;fm<4;fm++){
        #pragma unroll
        for (int fn=0;fn<4;fn++){
          acc0[fm][fn] = __builtin_amdgcn_mfma_f32_16x16x32_bf16(af[fm], b0f[fn], acc0[fm][fn],0,0,0);
          if (NB==2)
            acc1[fm][fn] = __builtin_amdgcn_mfma_f32_16x16x32_bf16(af[fm], b1f[fn], acc1[fm][fn],0,0,0);
        }
      }
    }
  }

  #pragma unroll
  for (int fm=0;fm<4;fm++){
    #pragma unroll
    for (int j=0;j<4;j++){
      int grow = wm*64 + fm*16 + lgrp*4 + j;
      if (row0+grow < cnt){
        int p = off + row0 + grow;
        if (EPI==0){
          u16* hrow = Hout + (size_t)p*N;
          #pragma unroll
          for (int fn=0;fn<4;fn++){
            int col = n0 + wn*64 + fn*16 + lrow;
            float g = acc0[fm][fn][j], u = acc1[fm][fn][j];
            hrow[col] = f2bf(g*u/(1.f+expf(-g)));
          }
        } else {
          int tok = pair_token[p];
          float wgt = pair_w[p];
          float* orow = Out + (size_t)tok*N;
          #pragma unroll
          for (int fn=0;fn<4;fn++){
            int col = n0 + wn*64 + fn*16 + lrow;
            atomicAdd(orow + col, wgt*acc0[fm][fn][j]);
          }
        }
      }
    }
  }
}

extern "C" void kernel_launch(void* const* d_in, const int* in_sizes, int n_in,
                              void* d_out, int out_size, void* d_ws, size_t ws_size,
                              hipStream_t stream) {
  const float* x  = (const float*)d_in[0];
  const float* gw = (const float*)d_in[1];
  const float* wg = (const float*)d_in[2];
  const float* wu = (const float*)d_in[3];
  const float* wd = (const float*)d_in[4];
  float* out = (float*)d_out;

  const size_t WT_BYTES = (size_t)NEXP*MDIM*HDIM*2;  // 161,480,704

  char* p = (char*)d_ws;
  u16* wg_t = (u16*)p;                 // [E][M][H] bf16
  u16* wd_t = (u16*)p;                 // [E][H][M] bf16, overwrites wg_t after stage 1
  p += WT_BYTES;
  u16* wu_t = (u16*)p; p += WT_BYTES;  // [E][M][H] bf16
  u16* xb   = (u16*)p; p += (size_t)T_TOK*HDIM*2;   // 16.8 MB
  u16* hbuf = (u16*)p; p += (size_t)NPAIR*MDIM*2;   // 69.2 MB
  int*   topk_idx   = (int*)p;   p += NPAIR*4;
  float* topk_w     = (float*)p; p += NPAIR*4;
  int*   pair_token = (int*)p;   p += NPAIR*4;
  float* pair_w     = (float*)p; p += NPAIR*4;
  int*   counts     = (int*)p;   p += 128;
  int*   offsets    = (int*)p;   p += 128;
  int*   cursor     = (int*)p;   p += 128;

  hipMemsetAsync(counts, 0, 128, stream);
  cvt_kernel<<<T_TOK*HDIM/8/256, 256, 0, stream>>>(x, xb, T_TOK*HDIM/8);
  gate_kernel<<<T_TOK/4, 256, 0, stream>>>(x, gw, topk_idx, topk_w, counts);
  scan_kernel<<<1, 64, 0, stream>>>(counts, offsets, cursor);
  fill_kernel<<<T_TOK/256, 256, 0, stream>>>(topk_idx, topk_w, offsets, cursor, pair_token, pair_w);
  hipMemsetAsync(out, 0, (size_t)out_size*4, stream);

  // weights -> bf16 transposed
  transpose_cvt<<<dim3(MDIM/64, HDIM/64, NEXP), 256, 0, stream>>>(wg, wg_t, HDIM, MDIM);
  transpose_cvt<<<dim3(MDIM/64, HDIM/64, NEXP), 256, 0, stream>>>(wu, wu_t, HDIM, MDIM);

  // stage 1: fused gate+up+silu  (h = silu(x@wg) * (x@wu))
  gemm2<2,true,0><<<dim3(MDIM/128, T_TOK/128, NEXP), 256, 0, stream>>>(
      xb, wg_t, wu_t, hbuf, nullptr, counts, offsets, pair_token, pair_w, HDIM, MDIM);

  // wd -> bf16 transposed (reuses wg_t space; stream-ordered after stage 1)
  transpose_cvt<<<dim3(HDIM/64, MDIM/64, NEXP), 256, 0, stream>>>(wd, wd_t, MDIM, HDIM);

  // stage 2: y += w_p * (h @ wd)
  gemm2<1,false,1><<<dim3(HDIM/128, T_TOK/128, NEXP), 256, 0, stream>>>(
      hbuf, wd_t, nullptr, nullptr, out, counts, offsets, pair_token, pair_w, MDIM, HDIM);
}